// Round 8
// baseline (172.654 us; speedup 1.0000x reference)
//
#include <hip/hip_runtime.h>
#include <math.h>

// Round-8: decisive k1 experiment. R7 (launch_bounds fix) was null => the
// VGPR/ILP theory is dead. Two surviving theories for k1's ~43us:
//   T-A: geometry/latency (341 fat 1024-thr blocks = 1.33/CU, poor spread)
//   T-B: external (harness 268MB fill's HBM writeback drain, ~43us, charged
//        to whatever runs first)
// This round changes ONLY k1: 1364 blocks x 256 threads (64 anchors/block,
// identical per-thread work; invBlk via atomicAdd at 256-anchor granularity,
// moved into the zeroed region). T-A predicts total ~145-152; T-B predicts
// null (~170). Everything else byte-identical to R7.

#define NANCH 87296
#define NF 4256        // 1000*4 + 256 finalists
#define CAPD 128       // max neighbors per column
#define NITER 16       // 15 scan iterations + initial keep
#define BCAP 512       // boundary-bin buffer per level
#define EC 8192        // LDS edge cap (packed i<<16|j)
#define NBLK 341       // 256-anchor groups; level boundaries are multiples of 256
#define K1B 1364       // k1 blocks (1364*64 = 87296 anchors)
#define BASE20 0xBD4CCu
#define NB20 9216      // padded to 1024 threads x 9 bins
#define BPT 9          // bins per k2 thread

struct InPtrs {
    const float* cls[5];
    const float* reg[5];
    const float* loc;
};

// workspace layout (invBlk now inside the zeroed region: k1 atomicAdds it)
constexpr size_t SZ_HIST  = 5ull * NB20 * 4;            // 184,320
constexpr size_t OFF_HIST = 0;
constexpr size_t OFF_CNT  = OFF_HIST + SZ_HIST;
constexpr size_t OFF_CTR  = OFF_CNT + (size_t)NF * 4;   // [0]=finCount,[1..5]=bCount,[8]=k3done
constexpr size_t OFF_INVB = OFF_CTR + 128;
constexpr size_t ZERO_SZ  = OFF_INVB + (size_t)NBLK * 4;
constexpr size_t OFF_SBITS = ((ZERO_SZ + 255) / 256) * 256;
constexpr size_t OFF_CLSV  = OFF_SBITS + (size_t)NANCH * 4;
constexpr size_t OFF_PAR   = OFF_CLSV + (size_t)NANCH * 4;  // B*[5]@0,r*[5]@8,rNeg[5]@16
constexpr size_t OFF_INVO  = OFF_PAR + 128;
constexpr size_t OFF_FINK  = ((OFF_INVO + (size_t)NBLK * 4 + 255) / 256) * 256;
constexpr size_t OFF_BBUF  = OFF_FINK + (size_t)NF * 8;
constexpr size_t OFF_SBOX  = OFF_BBUF + 5ull * BCAP * 8;
constexpr size_t OFF_SSC   = OFF_SBOX + (size_t)NF * 16;
constexpr size_t OFF_SCV   = OFF_SSC + (size_t)NF * 4;
constexpr size_t OFF_SAR   = OFF_SCV + (size_t)NF * 4;
constexpr size_t OFF_NBR   = OFF_SAR + (size_t)NF * 4;

__device__ __forceinline__ void lvl_of(int a, int& lev, int& idx) {
    if (a < 65536)      { lev = 0; idx = a; }
    else if (a < 81920) { lev = 1; idx = a - 65536; }
    else if (a < 86016) { lev = 2; idx = a - 81920; }
    else if (a < 87040) { lev = 3; idx = a - 86016; }
    else                { lev = 4; idx = a - 87040; }
}

__device__ __forceinline__ unsigned int fkey(float f) {
    unsigned int u = __float_as_uint(f);
    return u ^ ((u & 0x80000000u) ? 0xFFFFFFFFu : 0x80000000u);
}
__device__ __forceinline__ float funkey(unsigned int k) {
    return __uint_as_float(k ^ ((k & 0x80000000u) ? 0x80000000u : 0xFFFFFFFFu));
}
__device__ __forceinline__ unsigned int bin20_addr(unsigned int v) {
    unsigned int owner = v / BPT;
    unsigned int i = v - owner * BPT;
    return (i << 10) | owner;
}
__device__ __forceinline__ unsigned int ald(const unsigned int* p) {
    return __hip_atomic_load((unsigned int*)p, __ATOMIC_RELAXED, __HIP_MEMORY_SCOPE_AGENT);
}
__device__ __forceinline__ void ast64(unsigned long long* p, unsigned long long v) {
    __hip_atomic_store(p, v, __ATOMIC_RELAXED, __HIP_MEMORY_SCOPE_AGENT);
}
__device__ __forceinline__ unsigned long long ald64(const unsigned long long* p) {
    return __hip_atomic_load((unsigned long long*)p, __ATOMIC_RELAXED, __HIP_MEMORY_SCOPE_AGENT);
}

// ---------------------------------------------------------------- K1
// 1364 x 256: 64 anchors/block, 4 threads/anchor. Same per-thread work as
// before; ~5.3 blocks/CU for latency hiding (was 1.33 fat blocks).
__global__ __launch_bounds__(256) void k1_score(InPtrs P, unsigned int* hist,
        unsigned int* sbits, unsigned int* clsv, unsigned int* invBlk) {
    int t = threadIdx.x;
    int a = blockIdx.x * 64 + (t >> 2);
    int k = t & 3;
    int lev, idx; lvl_of(a, lev, idx);
    const float4* row = (const float4*)(P.cls[lev] + (size_t)idx * 80);
    float4 v0 = row[0 * 4 + k];
    float4 v1 = row[1 * 4 + k];
    float4 v2 = row[2 * 4 + k];
    float4 v3 = row[3 * 4 + k];
    float4 v4 = row[4 * 4 + k];
    float best = -INFINITY; int bi = 0;
    float4 v[5] = { v0, v1, v2, v3, v4 };
    #pragma unroll
    for (int q = 0; q < 5; ++q) {
        int c0 = q * 16 + k * 4;
        if (v[q].x > best) { best = v[q].x; bi = c0 + 0; }
        if (v[q].y > best) { best = v[q].y; bi = c0 + 1; }
        if (v[q].z > best) { best = v[q].z; bi = c0 + 2; }
        if (v[q].w > best) { best = v[q].w; bi = c0 + 3; }
    }
    #pragma unroll
    for (int m = 1; m < 4; m <<= 1) {
        float ob = __shfl_xor(best, m, 64);
        int  obi = __shfl_xor(bi, m, 64);
        if (ob > best || (ob == best && obi < bi)) { best = ob; bi = obi; }
    }
    bool lead = (k == 0);
    unsigned int valid = 0;
    if (lead) {
        float score = 1.0f / (1.0f + expf(-best));
        valid = (score > 0.05f) ? 1u : 0u;
        float psm = valid ? score : -1.0f;
        unsigned int sb = fkey(psm);
        sbits[a] = sb;
        clsv[a] = (unsigned int)(bi + 1) | (valid << 31);
        if (valid) {
            unsigned int bin = (sb >> 12) - BASE20;   // in [0, 9012]
            atomicAdd(&hist[(size_t)lev * NB20 + bin20_addr(bin)], 1u);
        }
    }
    __shared__ unsigned int wv[4];
    unsigned long long mv = __ballot(lead && valid);
    int lane = t & 63, w = t >> 6;
    if (lane == 0) wv[w] = (unsigned int)__popcll(mv);
    __syncthreads();
    if (t == 0) {
        unsigned int s = wv[0] + wv[1] + wv[2] + wv[3];
        atomicAdd(&invBlk[blockIdx.x >> 2], 64u - s);   // 256-anchor granularity
    }
}

// ---------------------------------------------------------------- K2
__global__ __launch_bounds__(1024) void k2_scan(const unsigned int* hist,
        const unsigned int* invBlk, unsigned int* params, unsigned int* invOff) {
    int t = threadIdx.x;
    if (blockIdx.x == 5) {
        __shared__ unsigned int sv[512];
        __shared__ unsigned int orig[512];
        if (t < 512) {
            unsigned int v = (t < NBLK) ? invBlk[t] : 0u;
            sv[t] = v; orig[t] = v;
        }
        __syncthreads();
        for (int off = 1; off < 512; off <<= 1) {
            unsigned int add = 0;
            if (t < 512 && t >= off) add = sv[t - off];
            __syncthreads();
            if (t < 512) sv[t] += add;
            __syncthreads();
        }
        if (t < NBLK) {
            int segStart = (t < 256) ? 0 : (t < 320) ? 256 : (t < 336) ? 320
                         : (t < 340) ? 336 : 340;
            invOff[t] = sv[t] - orig[t] - (segStart > 0 ? sv[segStart - 1] : 0u);
        }
        return;
    }
    int lev = blockIdx.x;
    unsigned int K = (lev == 4) ? 256u : 1000u;
    const unsigned int* h = hist + (size_t)lev * NB20;
    __shared__ unsigned int seg[1024];
    __shared__ unsigned int suf[1024];
    unsigned int hc[BPT];
    unsigned int s = 0;
    #pragma unroll
    for (int i = 0; i < BPT; ++i) { hc[i] = h[(i << 10) | t]; s += hc[i]; }
    seg[t] = s;
    suf[t] = s;
    __syncthreads();
    for (int off = 1; off < 1024; off <<= 1) {
        unsigned int v = suf[t];
        unsigned int add = (t + off < 1024) ? suf[t + off] : 0u;
        __syncthreads();
        suf[t] = v + add;
        __syncthreads();
    }
    unsigned int totValid = suf[0];
    if (totValid >= K) {
        unsigned int excl = suf[t] - seg[t];
        if (excl < K && excl + seg[t] >= K) {
            unsigned int cum = excl;
            for (int i = BPT - 1; i >= 0; --i) {
                unsigned int c = hc[i];
                if (cum + c >= K) {
                    params[lev] = (unsigned int)(t * BPT + i);
                    params[8 + lev] = K - cum;
                    params[16 + lev] = 0;
                    break;
                }
                cum += c;
            }
        }
    } else if (t == 0) {
        params[lev] = 0;              // all valid pass (valid bins > 0)
        params[8 + lev] = 0;
        params[16 + lev] = K - totValid;
    }
}

// ---------------------------------------------------------------- K3
// Compaction + tail-block boundary resolution (retire election, R4-validated).
__global__ __launch_bounds__(256) void k3_compact(const unsigned int* sbits,
        const unsigned int* clsv, const unsigned int* params,
        const unsigned int* invOff, unsigned long long* finKeys,
        unsigned int* ctrs, unsigned long long* bBuf) {
    int blk = blockIdx.x;
    int t = threadIdx.x;
    int a = blk * 256 + t;
    int lev, idx; lvl_of(a, lev, idx);
    unsigned int sb = sbits[a];
    unsigned int cv = clsv[a];
    unsigned int bin = (sb >> 12) - BASE20;   // meaningful for valid only
    unsigned int Bs = params[lev];
    unsigned int rNeg = params[16 + lev];
    unsigned int valid = cv >> 31;
    int lane = t & 63, w = t >> 6;
    unsigned long long lt = (1ull << lane) - 1ull;
    __shared__ unsigned int wInv[4], wFin[4], wB[4];
    __shared__ unsigned int baseFin, baseB;
    unsigned long long mInv = __ballot(valid == 0u);
    if (lane == 0) wInv[w] = (unsigned int)__popcll(mInv);
    __syncthreads();
    unsigned int invRank = invOff[blk] + (unsigned int)__popcll(mInv & lt);
    for (int i = 0; i < w; ++i) invRank += wInv[i];
    bool isFin, isB;
    if (valid) {
        isFin = (bin > Bs);
        isB   = (bin == Bs);
    } else {
        isFin = (rNeg > 0) && (invRank < rNeg);
        isB   = false;
    }
    unsigned long long mFin = __ballot(isFin);
    unsigned long long mB   = __ballot(isB);
    if (lane == 0) { wFin[w] = (unsigned int)__popcll(mFin); wB[w] = (unsigned int)__popcll(mB); }
    __syncthreads();
    if (t == 0) {
        unsigned int tf = wFin[0] + wFin[1] + wFin[2] + wFin[3];
        unsigned int tb = wB[0] + wB[1] + wB[2] + wB[3];
        baseFin = tf ? atomicAdd(&ctrs[0], tf) : 0u;
        baseB   = tb ? atomicAdd(&ctrs[1 + lev], tb) : 0u;
    }
    __syncthreads();
    if (isFin || isB) {
        unsigned int composite = ((unsigned int)lev << 16) | (unsigned int)idx;
        unsigned int inv = (~composite) & 0x7FFFFu;
        unsigned int low = (inv << 13) | (valid << 7) | (cv & 0x7Fu);
        unsigned long long key = ((unsigned long long)sb << 32) | low;
        if (isFin) {
            unsigned int p = baseFin + (unsigned int)__popcll(mFin & lt);
            for (int i = 0; i < w; ++i) p += wFin[i];
            if (p < NF) finKeys[p] = key;
        } else {
            unsigned int p = baseB + (unsigned int)__popcll(mB & lt);
            for (int i = 0; i < w; ++i) p += wB[i];
            if (p < BCAP) ast64(&bBuf[(size_t)lev * BCAP + p], key);
        }
    }
    // ---- tail election: last block resolves the boundary bins -------------
    __shared__ unsigned int isLast;
    __shared__ unsigned long long kb[BCAP];
    __shared__ unsigned int posS;
    __syncthreads();                // all waves' stores drained
    if (t == 0) {
        asm volatile("s_waitcnt vmcnt(0)" ::: "memory");
        unsigned int r = __hip_atomic_fetch_add(&ctrs[8], 1u,
                             __ATOMIC_RELAXED, __HIP_MEMORY_SCOPE_AGENT);
        isLast = (r == (unsigned int)(NBLK - 1)) ? 1u : 0u;
    }
    __syncthreads();
    if (!isLast) return;
    unsigned int fc = ald(&ctrs[0]);
    if (fc > NF) fc = NF;
    if (t == 0) posS = fc;
    __syncthreads();
    for (int blev = 0; blev < 5; ++blev) {
        unsigned int bc = ald(&ctrs[1 + blev]);
        int n = (bc > BCAP) ? BCAP : (int)bc;
        int r = (int)params[8 + blev];
        if (r > n) r = n;
        if (r > 0) {
            for (int i = t; i < n; i += 256)
                kb[i] = ald64(&bBuf[(size_t)blev * BCAP + i]);
            __syncthreads();
            for (int i = t; i < n; i += 256) {
                unsigned long long my = kb[i];
                unsigned int c = 0;
                for (int j = 0; j < n; ++j) c += (kb[j] > my) ? 1u : 0u;
                if (c < (unsigned int)r) {
                    unsigned int p = atomicAdd(&posS, 1u);
                    if (p < NF) finKeys[p] = my;
                }
            }
            __syncthreads();
        }
    }
    for (int i = (int)posS + t; i < NF; i += 256)   // defensive (posS==NF normally)
        finKeys[i] = (unsigned long long)i;
}

// ---------------------------------------------------------------- K5
// Pure rank + gather: 67 blocks x 1024 threads, 64 finalists per block.
__global__ __launch_bounds__(1024) void k5_rank(InPtrs P,
        const unsigned long long* finKeys,
        float4* sBox, float* sScore, unsigned int* sCV, float* sArea) {
    __shared__ __align__(16) unsigned long long keys[NF];
    __shared__ unsigned int rnk[64];
    int t = threadIdx.x;
    {   // vectorized key load (NF = 2128 ulonglong2)
        const ulonglong2* src = (const ulonglong2*)finKeys;
        ulonglong2* dst = (ulonglong2*)keys;
        for (int i = t; i < NF / 2; i += 1024) dst[i] = src[i];
    }
    if (t < 64) rnk[t] = 0;
    __syncthreads();
    int lf = t & 63;
    int seg = t >> 6;                       // 16 segments of 266 keys
    int f = blockIdx.x * 64 + lf;
    unsigned long long my = (f < NF) ? keys[f] : 0ull;
    if (f < NF) {
        unsigned int c = 0;
        const ulonglong2* kp = (const ulonglong2*)keys + seg * 133;
        #pragma unroll 4
        for (int i = 0; i < 133; ++i) {
            ulonglong2 v = kp[i];
            c += (v.x > my) ? 1u : 0u;
            c += (v.y > my) ? 1u : 0u;
        }
        atomicAdd(&rnk[lf], c);
    }
    __syncthreads();
    if (seg == 0 && f < NF) {
        unsigned int r = rnk[lf];
        unsigned int sb  = (unsigned int)(my >> 32);
        unsigned int low = (unsigned int)my;
        unsigned int composite = (~(low >> 13)) & 0x7FFFFu;
        int lev = composite >> 16;
        int idx = composite & 0xFFFF;
        float4 b = ((const float4*)P.reg[lev])[idx];
        float vy1 = P.loc[0], vx1 = P.loc[1], vy2 = P.loc[2], vx2 = P.loc[3];
        float y1 = fmaxf(b.x, vy1), x1 = fmaxf(b.y, vx1);
        float y2 = fminf(b.z, vy2), x2 = fminf(b.w, vx2);
        float area = __fmul_rn(fmaxf(y2 - y1, 0.0f), fmaxf(x2 - x1, 0.0f));
        unsigned int valid = (low >> 7) & 1u;
        sBox[r] = make_float4(y1, x1, y2, x2);
        sScore[r] = valid ? funkey(sb) : 0.0f;
        sCV[r] = (low & 0x7Fu) | (valid << 31);
        sArea[r] = area;
    }
}

// ---------------------------------------------------------------- K6
__global__ __launch_bounds__(256) void k6_adj(const float4* sBox,
        const float* sArea, unsigned int* cnt, unsigned short* nbr) {
    int L = blockIdx.x;
    float fr = sqrtf(8.0f * (float)L + 1.0f);
    int jt = (int)((fr - 1.0f) * 0.5f);
    while ((jt + 1) * (jt + 2) / 2 <= L) jt++;
    while (jt * (jt + 1) / 2 > L) jt--;
    int it = L - jt * (jt + 1) / 2;
    __shared__ float4 cb[64]; __shared__ float ca[64];
    __shared__ float4 rb[64]; __shared__ float ra[64];
    int t = threadIdx.x;
    if (t < 64) {
        int j = jt * 64 + t;
        if (j < NF) { cb[t] = sBox[j]; ca[t] = sArea[j]; }
        int i = it * 64 + t;
        if (i < NF) { rb[t] = sBox[i]; ra[t] = sArea[i]; }
    }
    __syncthreads();
    int lj = t & 63;
    int j = jt * 64 + lj;
    if (j >= NF) return;
    float4 B = cb[lj]; float ab = ca[lj];
    for (int li = (t >> 6); li < 64; li += 4) {
        int i = it * 64 + li;
        if (i >= j) continue;
        float4 A = rb[li]; float aa = ra[li];
        float iy1 = fmaxf(A.x, B.x), ix1 = fmaxf(A.y, B.y);
        float iy2 = fminf(A.z, B.z), ix2 = fminf(A.w, B.w);
        float ih = fmaxf(iy2 - iy1, 0.0f), iw = fmaxf(ix2 - ix1, 0.0f);
        float inter = __fmul_rn(ih, iw);
        float uni = __fsub_rn(__fadd_rn(aa, ab), inter);
        float iou = __fdiv_rn(inter, fmaxf(uni, 1e-9f));
        if (iou > 0.5f) {
            unsigned int p = atomicAdd(&cnt[j], 1u);
            if (p < CAPD) nbr[(size_t)j * CAPD + p] = (unsigned short)i;
        }
    }
}

// ---------------------------------------------------------------- K7
// Edge-parallel NMS with convergence early-exit.
__global__ __launch_bounds__(1024) void k7_nms(InPtrs P, const float4* sBox,
        const float* sScore, const unsigned int* sCV, const unsigned int* cnt,
        const unsigned short* nbr, float* out) {
    __shared__ unsigned int edges[EC];
    __shared__ __align__(4) unsigned char bufA[NF];
    __shared__ __align__(4) unsigned char bufB[NF];
    __shared__ unsigned int wsum[16];
    __shared__ float ploc[6];
    __shared__ unsigned int chg;
    int t = threadIdx.x;
    int lane = t & 63, wid = t >> 6;
    if (t < 6) ploc[t] = P.loc[t];
    const int CH = 5;
    unsigned int dq[CH];
    unsigned int s = 0;
    #pragma unroll
    for (int q = 0; q < CH; ++q) {
        int j = t * CH + q;
        unsigned int d = 0;
        if (j < NF) { d = cnt[j]; if (d > CAPD) d = CAPD; }
        dq[q] = d; s += d;
    }
    unsigned int sc = s;
    #pragma unroll
    for (int o = 1; o < 64; o <<= 1) {
        unsigned int n = __shfl_up(sc, o, 64);
        if (lane >= o) sc += n;
    }
    if (lane == 63) wsum[wid] = sc;
    if (t < 1064) ((unsigned int*)bufA)[t] = 0x01010101u;   // NF=4256=1064*4
    __syncthreads();
    unsigned int wbase = 0, tot = 0;
    #pragma unroll
    for (int i = 0; i < 16; ++i) {
        unsigned int v = wsum[i];
        if (i < wid) wbase += v;
        tot += v;
    }
    unsigned int E = tot;
    bool useLds = (E <= (unsigned int)EC);
    if (useLds) {
        unsigned int base = wbase + sc - s;   // exclusive prefix
        #pragma unroll
        for (int q = 0; q < CH; ++q) {
            int j = t * CH + q;
            if (j < NF) {
                unsigned int d = dq[q];
                const unsigned short* nl = nbr + (size_t)j * CAPD;
                for (unsigned int e = 0; e < d; ++e)
                    edges[base + e] = ((unsigned int)nl[e] << 16) | (unsigned int)j;
                base += d;
            }
        }
    }
    __syncthreads();
    unsigned char* cur = bufA; unsigned char* nxt = bufB;
    for (int itr = 0; itr < NITER; ++itr) {
        if (t < 1064) ((unsigned int*)nxt)[t] = 0x01010101u;
        __syncthreads();
        if (useLds) {
            for (int e = t; e < (int)E; e += 1024) {
                unsigned int pk = edges[e];
                if (cur[pk >> 16]) nxt[pk & 0xFFFFu] = 0;
            }
        } else {
            for (int j = t; j < NF; j += 1024) {
                unsigned int d = cnt[j]; if (d > CAPD) d = CAPD;
                const unsigned short* nl = nbr + (size_t)j * CAPD;
                unsigned int hit = 0;
                for (unsigned int e = 0; e < d; ++e)
                    hit |= (unsigned int)cur[nl[e]];
                if (hit) nxt[j] = 0;
            }
        }
        __syncthreads();
        if (t < 1064 &&
            ((unsigned int*)nxt)[t] != ((unsigned int*)cur)[t]) chg = 1;
        __syncthreads();
        unsigned int done = (chg == 0u);
        unsigned char* tm = cur; cur = nxt; nxt = tm;
        __syncthreads();
        if (t == 0) chg = 0;
        if (done) break;
    }
    // final keep & emit (wave-scan prefix)
    int base = t * CH;
    unsigned char kf[CH];
    unsigned int sum = 0;
    #pragma unroll
    for (int q = 0; q < CH; ++q) {
        int j = base + q;
        unsigned char v = 0;
        if (j < NF) v = cur[j] & (unsigned char)(sCV[j] >> 31);
        kf[q] = v; sum += v;
    }
    unsigned int sc2 = sum;
    #pragma unroll
    for (int o = 1; o < 64; o <<= 1) {
        unsigned int n = __shfl_up(sc2, o, 64);
        if (lane >= o) sc2 += n;
    }
    if (lane == 63) wsum[wid] = sc2;
    __syncthreads();
    unsigned int wbase2 = 0, keptTot = 0;
    #pragma unroll
    for (int i = 0; i < 16; ++i) {
        unsigned int v = wsum[i];
        if (i < wid) wbase2 += v;
        keptTot += v;
    }
    unsigned int run = wbase2 + sc2 - sum;
    float vy1 = ploc[0], vx1 = ploc[1], vy2 = ploc[2], vx2 = ploc[3];
    float sy = ploc[4] / fmaxf(vy2 - vy1, 1e-6f);
    float sx = ploc[5] / fmaxf(vx2 - vx1, 1e-6f);
    #pragma unroll
    for (int q = 0; q < CH; ++q) {
        int j = base + q;
        if (j >= NF) break;
        unsigned int slot = 0xFFFFFFFFu;
        float scv = 0.0f;
        if (kf[q]) {
            if (run < 100u) { slot = run; scv = sScore[j]; }
            run++;
        } else if (keptTot < 100u) {
            unsigned int nk = (unsigned int)j - run;
            unsigned int s2 = keptTot + nk;
            if (s2 < 100u) { slot = s2; scv = 0.0f; }
        }
        if (slot < 100u) {
            float4 b = sBox[j];
            out[slot * 4 + 0] = (b.x - vy1) * sy;
            out[slot * 4 + 1] = (b.y - vx1) * sx;
            out[slot * 4 + 2] = (b.z - vy1) * sy;
            out[slot * 4 + 3] = (b.w - vx1) * sx;
            out[400 + slot] = (float)(sCV[j] & 0x7Fu);
            out[500 + slot] = scv;
        }
    }
}

extern "C" void kernel_launch(void* const* d_in, const int* in_sizes, int n_in,
                              void* d_out, int out_size, void* d_ws, size_t ws_size,
                              hipStream_t stream) {
    (void)n_in; (void)out_size; (void)ws_size;
    InPtrs P;
    bool inter = (in_sizes[1] == 65536 * 4);
    for (int s = 0; s < 5; ++s) {
        P.cls[s] = (const float*)d_in[inter ? 2 * s : s];
        P.reg[s] = (const float*)d_in[inter ? 2 * s + 1 : 5 + s];
    }
    P.loc = (const float*)d_in[10];

    char* w = (char*)d_ws;
    unsigned int* hist   = (unsigned int*)(w + OFF_HIST);
    unsigned int* cnt    = (unsigned int*)(w + OFF_CNT);
    unsigned int* ctrs   = (unsigned int*)(w + OFF_CTR);
    unsigned int* sbits  = (unsigned int*)(w + OFF_SBITS);
    unsigned int* clsv   = (unsigned int*)(w + OFF_CLSV);
    unsigned int* params = (unsigned int*)(w + OFF_PAR);
    unsigned int* invBlk = (unsigned int*)(w + OFF_INVB);
    unsigned int* invOff = (unsigned int*)(w + OFF_INVO);
    unsigned long long* finKeys = (unsigned long long*)(w + OFF_FINK);
    unsigned long long* bBuf    = (unsigned long long*)(w + OFF_BBUF);
    float4* sBox  = (float4*)(w + OFF_SBOX);
    float* sScore = (float*)(w + OFF_SSC);
    unsigned int* sCV = (unsigned int*)(w + OFF_SCV);
    float* sArea  = (float*)(w + OFF_SAR);
    unsigned short* nbr = (unsigned short*)(w + OFF_NBR);

    hipMemsetAsync(d_ws, 0, ZERO_SZ, stream);
    k1_score<<<K1B, 256, 0, stream>>>(P, hist, sbits, clsv, invBlk);
    k2_scan<<<6, 1024, 0, stream>>>(hist, invBlk, params, invOff);
    k3_compact<<<NBLK, 256, 0, stream>>>(sbits, clsv, params, invOff, finKeys, ctrs, bBuf);
    k5_rank<<<67, 1024, 0, stream>>>(P, finKeys, sBox, sScore, sCV, sArea);
    k6_adj<<<2278, 256, 0, stream>>>(sBox, sArea, cnt, nbr);
    k7_nms<<<1, 1024, 0, stream>>>(P, sBox, sScore, sCV, cnt, nbr, (float*)d_out);
}